// Round 7
// baseline (236.363 us; speedup 1.0000x reference)
//
#include <hip/hip_runtime.h>
#include <hip/hip_bf16.h>
#include <math.h>

#define N_NODES 50000
#define N_EDGES 800000
#define D0 64
#define D1 128
#define D2 40

#define NB  256   // buckets
#define NPB 196   // nodes per bucket (256*196 = 50176 >= 50000)

// ---------------- bucketed CSR build ----------------
__global__ __launch_bounds__(256) void bucket_count_kernel(
        const int* __restrict__ dst, int* __restrict__ bcount, int E) {
    __shared__ int h[NB];
    int t = threadIdx.x;
    h[t] = 0;
    __syncthreads();
    int e0 = blockIdx.x * 2048;
    for (int i = t; i < 2048; i += 256) {
        int e = e0 + i;
        if (e < E) atomicAdd(&h[(unsigned)dst[e] / NPB], 1);
    }
    __syncthreads();
    if (h[t]) atomicAdd(&bcount[t], h[t]);
}

__global__ void bucket_scan_kernel(const int* __restrict__ bcount,
                                   int* __restrict__ bbase, int* __restrict__ bcursor) {
    __shared__ int sd[NB];
    int t = threadIdx.x;
    int v = bcount[t];
    sd[t] = v;
    __syncthreads();
    for (int off = 1; off < NB; off <<= 1) {
        int u = (t >= off) ? sd[t - off] : 0;
        __syncthreads();
        sd[t] += u;
        __syncthreads();
    }
    int ex = sd[t] - v;
    bbase[t] = ex;
    bcursor[t] = ex;
}

__global__ __launch_bounds__(256) void bucket_scatter_kernel(
        const int* __restrict__ src, const int* __restrict__ dst,
        int* __restrict__ bcursor, unsigned* __restrict__ ebuf, int E) {
    __shared__ int h[NB];
    __shared__ int base[NB];
    int t = threadIdx.x;
    int e0 = blockIdx.x * 4096;
    h[t] = 0;
    __syncthreads();
    for (int i = t; i < 4096; i += 256) {
        int e = e0 + i;
        if (e < E) atomicAdd(&h[(unsigned)dst[e] / NPB], 1);
    }
    __syncthreads();
    if (h[t] > 0) base[t] = atomicAdd(&bcursor[t], h[t]);
    h[t] = 0;
    __syncthreads();
    for (int i = t; i < 4096; i += 256) {
        int e = e0 + i;
        if (e < E) {
            unsigned d = (unsigned)dst[e];
            unsigned b = d / NPB;
            unsigned ld = d - b * NPB;
            int k = atomicAdd(&h[b], 1);
            ebuf[base[b] + k] = (ld << 17) | (unsigned)src[e];
        }
    }
}

__global__ __launch_bounds__(256) void bucket_fill_kernel(
        const unsigned* __restrict__ ebuf, const int* __restrict__ bbase,
        int* __restrict__ rowptr, int* __restrict__ csr, int E, int N) {
    __shared__ int cnt[256];
    __shared__ int sd[256];
    int b = blockIdx.x, t = threadIdx.x;
    int s0 = bbase[b];
    int s1 = (b < NB - 1) ? bbase[b + 1] : E;
    int lo = b * NPB;
    cnt[t] = 0;
    __syncthreads();
    for (int i = s0 + t; i < s1; i += 256)
        atomicAdd(&cnt[ebuf[i] >> 17], 1);
    __syncthreads();
    int v = cnt[t];
    sd[t] = v;
    __syncthreads();
    for (int off = 1; off < 256; off <<= 1) {
        int u = (t >= off) ? sd[t - off] : 0;
        __syncthreads();
        sd[t] += u;
        __syncthreads();
    }
    int ex = sd[t] - v;
    int node = lo + t;
    if (t < NPB && node < N) rowptr[node] = s0 + ex;
    cnt[t] = s0 + ex;
    __syncthreads();
    for (int i = s0 + t; i < s1; i += 256) {
        unsigned pk = ebuf[i];
        int p = atomicAdd(&cnt[pk >> 17], 1);
        csr[p] = (int)(pk & 0x1FFFFu);
    }
    if (b == NB - 1 && t == 0) rowptr[N] = E;
}

// ---------------- cast x to bf16 ----------------

__global__ void cast_x_kernel(const float* __restrict__ x, __hip_bfloat16* __restrict__ xh, int n) {
    int i = (blockIdx.x * blockDim.x + threadIdx.x) * 4;
    if (i < n) {
        float4 v = *(const float4*)(x + i);
        xh[i + 0] = __float2bfloat16(v.x);
        xh[i + 1] = __float2bfloat16(v.y);
        xh[i + 2] = __float2bfloat16(v.z);
        xh[i + 3] = __float2bfloat16(v.w);
    }
}

// ---------------- agg1: 8 edges/wave-instr, 8 lanes x 8 bf16 per edge ----------------

__global__ void agg1_kernel(const __hip_bfloat16* __restrict__ xh, const int* __restrict__ rowptr,
                            const int* __restrict__ csr, float* __restrict__ agg, int N) {
    int wid = (blockIdx.x * blockDim.x + threadIdx.x) >> 6;
    int lane = threadIdx.x & 63;
    if (wid >= N) return;
    int beg = rowptr[wid], end = rowptr[wid + 1];
    int deg = end - beg;
    int l = lane & 7, g = lane >> 3;
    float acc[8];
#pragma unroll
    for (int k = 0; k < 8; ++k) acc[k] = 0.f;
    int jmax = (deg + 7) >> 3;
    for (int j = 0; j < jmax; j += 2) {
        int s[2]; float w[2];
#pragma unroll
        for (int u = 0; u < 2; ++u) {
            int slot = (j + u) * 8 + g;
            int e = beg + slot;
            e = (e < end) ? e : (end - 1);
            s[u] = csr[e];
            w[u] = (slot < deg) ? 1.f : 0.f;
        }
#pragma unroll
        for (int u = 0; u < 2; ++u) {
            uint4 v = *(const uint4*)((const unsigned short*)xh + (size_t)s[u] * D0 + l * 8);
            float f0 = __uint_as_float(v.x << 16), f1 = __uint_as_float(v.x & 0xffff0000u);
            float f2 = __uint_as_float(v.y << 16), f3 = __uint_as_float(v.y & 0xffff0000u);
            float f4 = __uint_as_float(v.z << 16), f5 = __uint_as_float(v.z & 0xffff0000u);
            float f6 = __uint_as_float(v.w << 16), f7 = __uint_as_float(v.w & 0xffff0000u);
            acc[0] = fmaf(w[u], f0, acc[0]); acc[1] = fmaf(w[u], f1, acc[1]);
            acc[2] = fmaf(w[u], f2, acc[2]); acc[3] = fmaf(w[u], f3, acc[3]);
            acc[4] = fmaf(w[u], f4, acc[4]); acc[5] = fmaf(w[u], f5, acc[5]);
            acc[6] = fmaf(w[u], f6, acc[6]); acc[7] = fmaf(w[u], f7, acc[7]);
        }
    }
#pragma unroll
    for (int off = 8; off <= 32; off <<= 1) {
#pragma unroll
        for (int k = 0; k < 8; ++k) acc[k] += __shfl_xor(acc[k], off);
    }
    float inv = 1.f / (float)max(deg, 1);
    if (g == 0) {
        float4 o; o.x = acc[0] * inv; o.y = acc[1] * inv; o.z = acc[2] * inv; o.w = acc[3] * inv;
        *(float4*)(agg + (size_t)wid * D0 + l * 8) = o;
    } else if (g == 1) {
        float4 o; o.x = acc[4] * inv; o.y = acc[5] * inv; o.z = acc[6] * inv; o.w = acc[7] * inv;
        *(float4*)(agg + (size_t)wid * D0 + l * 8 + 4) = o;
    }
}

// ---------------- agg2 + log_softmax (fused) ----------------

__global__ void agg2_kernel(const float* __restrict__ p2, const float* __restrict__ r2,
                            const int* __restrict__ rowptr, const int* __restrict__ csr,
                            float* __restrict__ out, float* __restrict__ out2, int N) {
    int wid = (blockIdx.x * blockDim.x + threadIdx.x) >> 6;
    int lane = threadIdx.x & 63;
    if (wid >= N) return;
    int beg = rowptr[wid], end = rowptr[wid + 1];
    int deg = end - beg;
    int g = lane / 10;
    int l = lane - g * 10;
    bool gv = g < 6;
    float ax = 0.f, ay = 0.f, az = 0.f, aw = 0.f;
    int jmax = (deg + 5) / 6;
    for (int j = 0; j < jmax; j += 4) {
        int s[4]; float w[4];
#pragma unroll
        for (int u = 0; u < 4; ++u) {
            int slot = (j + u) * 6 + g;
            int e = beg + slot;
            e = (e < end) ? e : (end - 1);
            s[u] = csr[e];
            w[u] = (gv && slot < deg) ? 1.f : 0.f;
        }
#pragma unroll
        for (int u = 0; u < 4; ++u) {
            float4 v = *(const float4*)(p2 + (size_t)s[u] * D2 + l * 4);
            ax = fmaf(w[u], v.x, ax); ay = fmaf(w[u], v.y, ay);
            az = fmaf(w[u], v.z, az); aw = fmaf(w[u], v.w, aw);
        }
    }
    {
        float bx = __shfl(ax, lane + 30), by = __shfl(ay, lane + 30),
              bz = __shfl(az, lane + 30), bw = __shfl(aw, lane + 30);
        if (g < 3) { ax += bx; ay += by; az += bz; aw += bw; }
        bx = __shfl(ax, lane + 20); by = __shfl(ay, lane + 20);
        bz = __shfl(az, lane + 20); bw = __shfl(aw, lane + 20);
        if (g == 0) { ax += bx; ay += by; az += bz; aw += bw; }
        bx = __shfl(ax, lane + 10); by = __shfl(ay, lane + 10);
        bz = __shfl(az, lane + 10); bw = __shfl(aw, lane + 10);
        if (g == 0) { ax += bx; ay += by; az += bz; aw += bw; }
    }
    float inv = 1.f / (float)max(deg, 1);
    bool wr = (lane < 10);
    float4 h2;
    if (wr) {
        float4 rr = *(const float4*)(r2 + (size_t)wid * D2 + lane * 4);
        h2.x = rr.x + ax * inv; h2.y = rr.y + ay * inv;
        h2.z = rr.z + az * inv; h2.w = rr.w + aw * inv;
        *(float4*)(out + (size_t)wid * D2 + lane * 4) = h2;
    }
    float m = wr ? fmaxf(fmaxf(h2.x, h2.y), fmaxf(h2.z, h2.w)) : -INFINITY;
#pragma unroll
    for (int off = 1; off < 64; off <<= 1) m = fmaxf(m, __shfl_xor(m, off));
    float s = 0.f;
    if (wr) s = expf(h2.x - m) + expf(h2.y - m) + expf(h2.z - m) + expf(h2.w - m);
#pragma unroll
    for (int off = 1; off < 64; off <<= 1) s += __shfl_xor(s, off);
    if (wr) {
        float lg = m + logf(s);
        float4 o; o.x = h2.x - lg; o.y = h2.y - lg; o.z = h2.z - lg; o.w = h2.w - lg;
        *(float4*)(out2 + (size_t)wid * D2 + lane * 4) = o;
    }
}

// ---------------- GEMM 1: h = relu(x@W1r + agg1@W1l + b1) ----------------
// Column-split: each block does 64 of 128 output cols (Wc 32KB -> 4 blocks/CU).
// Thread: 8 rows x 4 cols; tile = 128 rows; ping-pong prefetch of row chunks.
__global__ __launch_bounds__(256) void gemm1_kernel(
        const float* __restrict__ x, const float* __restrict__ agg,
        const float* __restrict__ W1l, const float* __restrict__ W1r,
        const float* __restrict__ b1, float* __restrict__ h, int N) {
    __shared__ float Wc[128 * 64];   // K rows 0..63 = W1r, 64..127 = W1l; 64-col slice
    int t = threadIdx.x;
    int ch = blockIdx.x & 1;         // column half
    {
        for (int i = t; i < 2048; i += 256) {     // 2048 float4 = 8192 floats
            int row = i >> 4, c4 = i & 15;
            const float* Wsrc = (row < 64) ? W1r : W1l;
            int k = row & 63;
            ((float4*)Wc)[i] = *(const float4*)(Wsrc + k * 128 + ch * 64 + c4 * 4);
        }
    }
    __syncthreads();
    int jc = t & 15, j0 = jc * 4;
    int rg = t >> 4;                 // 0..15, 8 rows each -> 128 rows/tile
    float4 bb = *(const float4*)(b1 + ch * 64 + j0);
    int ntiles = (N + 127) >> 7;
    int nblk = gridDim.x >> 1;
    for (int tile = blockIdx.x >> 1; tile < ntiles; tile += nblk) {
        int r0 = tile * 128 + rg * 8;
        size_t roff[8];
#pragma unroll
        for (int i = 0; i < 8; ++i) {
            int r = r0 + i;
            roff[i] = (size_t)((r < N) ? r : (N - 1)) * D0;   // x and agg share stride
        }
        float acc[8][4];
#pragma unroll
        for (int i = 0; i < 8; ++i) {
            acc[i][0] = bb.x; acc[i][1] = bb.y; acc[i][2] = bb.z; acc[i][3] = bb.w;
        }
        float4 va[8], vb[8];
#pragma unroll
        for (int i = 0; i < 8; ++i) va[i] = *(const float4*)(x + roff[i]);
#pragma unroll 2
        for (int k4 = 0; k4 < 32; ++k4) {
            float4* vc = (k4 & 1) ? vb : va;
            float4* vn = (k4 & 1) ? va : vb;
            if (k4 < 31) {
                int kn = k4 + 1;
                const float* inp = (kn < 16) ? x : agg;
                int koff = (kn & 15) * 4;
#pragma unroll
                for (int i = 0; i < 8; ++i)
                    vn[i] = *(const float4*)(inp + roff[i] + koff);
            }
            const float* wbase = &Wc[(k4 * 4) * 64 + j0];
#pragma unroll
            for (int kk = 0; kk < 4; ++kk) {
                float4 w = *(const float4*)(wbase + kk * 64);
#pragma unroll
                for (int i = 0; i < 8; ++i) {
                    float s = ((const float*)&vc[i])[kk];
                    acc[i][0] += s * w.x; acc[i][1] += s * w.y;
                    acc[i][2] += s * w.z; acc[i][3] += s * w.w;
                }
            }
        }
#pragma unroll
        for (int i = 0; i < 8; ++i) {
            int r = r0 + i;
            if (r < N) {
                float4 o;
                o.x = fmaxf(acc[i][0], 0.f); o.y = fmaxf(acc[i][1], 0.f);
                o.z = fmaxf(acc[i][2], 0.f); o.w = fmaxf(acc[i][3], 0.f);
                *(float4*)(h + (size_t)r * D1 + ch * 64 + j0) = o;
            }
        }
    }
}

// ---------------- GEMM 2: p2 = h@W2l, r2 = h@W2r + b2 (ping-pong prefetch) ----------------
__global__ __launch_bounds__(320) void gemm2_kernel(
        const float* __restrict__ h,
        const float* __restrict__ W2l, const float* __restrict__ W2r,
        const float* __restrict__ b2,
        float* __restrict__ p2, float* __restrict__ r2, int N) {
    __shared__ float Wl[128 * 40];
    __shared__ float Wr[128 * 40];
    int t = threadIdx.x;
    {
        float4* a = (float4*)Wl;
        float4* b = (float4*)Wr;
        const float4* sa = (const float4*)W2l;
        const float4* sb = (const float4*)W2r;
        for (int i = t; i < 1280; i += 320) { a[i] = sa[i]; b[i] = sb[i]; }
    }
    __syncthreads();
    int jc = t % 10, j0 = jc * 4;
    int rg = t / 10;
    float4 bb = *(const float4*)(b2 + j0);
    int ntiles = (N + 127) >> 7;
    for (int tile = blockIdx.x; tile < ntiles; tile += gridDim.x) {
        int r0 = tile * 128 + rg * 4;
        size_t roff[4];
#pragma unroll
        for (int i = 0; i < 4; ++i) {
            int r = r0 + i;
            roff[i] = (size_t)((r < N) ? r : (N - 1)) * D1;
        }
        float accp[4][4], accr[4][4];
#pragma unroll
        for (int i = 0; i < 4; ++i) {
            accp[i][0] = 0.f; accp[i][1] = 0.f; accp[i][2] = 0.f; accp[i][3] = 0.f;
            accr[i][0] = bb.x; accr[i][1] = bb.y; accr[i][2] = bb.z; accr[i][3] = bb.w;
        }
        float4 va[4], vb[4];
#pragma unroll
        for (int i = 0; i < 4; ++i) va[i] = *(const float4*)(h + roff[i]);
#pragma unroll 2
        for (int k4 = 0; k4 < 32; ++k4) {
            float4* vc = (k4 & 1) ? vb : va;
            float4* vn = (k4 & 1) ? va : vb;
            if (k4 < 31) {
                int koff = (k4 + 1) * 4;
#pragma unroll
                for (int i = 0; i < 4; ++i)
                    vn[i] = *(const float4*)(h + roff[i] + koff);
            }
#pragma unroll
            for (int kk = 0; kk < 4; ++kk) {
                float4 wl = *(const float4*)(&Wl[(k4 * 4 + kk) * 40 + j0]);
                float4 wr = *(const float4*)(&Wr[(k4 * 4 + kk) * 40 + j0]);
#pragma unroll
                for (int i = 0; i < 4; ++i) {
                    float s = ((const float*)&vc[i])[kk];
                    accp[i][0] += s * wl.x; accp[i][1] += s * wl.y;
                    accp[i][2] += s * wl.z; accp[i][3] += s * wl.w;
                    accr[i][0] += s * wr.x; accr[i][1] += s * wr.y;
                    accr[i][2] += s * wr.z; accr[i][3] += s * wr.w;
                }
            }
        }
#pragma unroll
        for (int i = 0; i < 4; ++i) {
            int r = r0 + i;
            if (r < N) {
                float4 op, orr;
                op.x = accp[i][0]; op.y = accp[i][1]; op.z = accp[i][2]; op.w = accp[i][3];
                orr.x = accr[i][0]; orr.y = accr[i][1]; orr.z = accr[i][2]; orr.w = accr[i][3];
                *(float4*)(p2 + (size_t)r * D2 + j0) = op;
                *(float4*)(r2 + (size_t)r * D2 + j0) = orr;
            }
        }
    }
}

// ---------------- launch ----------------

extern "C" void kernel_launch(void* const* d_in, const int* in_sizes, int n_in,
                              void* d_out, int out_size, void* d_ws, size_t ws_size,
                              hipStream_t stream) {
    const float* x   = (const float*)d_in[0];
    const int*   ei  = (const int*)d_in[1];
    const float* W1l = (const float*)d_in[2];
    const float* W1r = (const float*)d_in[3];
    const float* b1  = (const float*)d_in[4];
    const float* W2l = (const float*)d_in[5];
    const float* W2r = (const float*)d_in[6];
    const float* b2  = (const float*)d_in[7];
    float* out = (float*)d_out;

    const int N = N_NODES;
    const int E = in_sizes[1] / 2;
    const int* src = ei;
    const int* dst = ei + E;

    char* p = (char*)d_ws;
    auto alloc = [&](size_t bytes) -> void* {
        void* r = (void*)p;
        p += (bytes + 255) & ~(size_t)255;
        return r;
    };
    int*      rowptr  = (int*)alloc((size_t)(N + 1) * 4);
    int*      csr     = (int*)alloc((size_t)E * 4);
    unsigned* ebuf    = (unsigned*)alloc((size_t)E * 4);
    int*      bcount  = (int*)alloc(NB * 4);
    int*      bbase   = (int*)alloc(NB * 4);
    int*      bcursor = (int*)alloc(NB * 4);
    __hip_bfloat16* xh = (__hip_bfloat16*)alloc((size_t)N * D0 * 2);
    float* agg1b = (float*)alloc((size_t)N * D0 * 4);
    float* hbuf  = (float*)alloc((size_t)N * D1 * 4);
    float* p2buf = (float*)alloc((size_t)N * D2 * 4);
    float* r2buf = (float*)alloc((size_t)N * D2 * 4);

    // bucketed CSR build
    hipMemsetAsync(bcount, 0, NB * 4, stream);
    bucket_count_kernel<<<(E + 2047) / 2048, 256, 0, stream>>>(dst, bcount, E);
    bucket_scan_kernel<<<1, NB, 0, stream>>>(bcount, bbase, bcursor);
    bucket_scatter_kernel<<<(E + 4095) / 4096, 256, 0, stream>>>(src, dst, bcursor, ebuf, E);
    bucket_fill_kernel<<<NB, 256, 0, stream>>>(ebuf, bbase, rowptr, csr, E, N);

    cast_x_kernel<<<(N * D0 / 4 + 255) / 256, 256, 0, stream>>>(x, xh, N * D0);

    // layer 1
    agg1_kernel<<<(N * 64 + 255) / 256, 256, 0, stream>>>(xh, rowptr, csr, agg1b, N);
    gemm1_kernel<<<2 * ((N + 127) / 128), 256, 0, stream>>>(x, agg1b, W1l, W1r, b1, hbuf, N);

    // layer 2: project first (linearity), gather 40-dim, fused log_softmax
    gemm2_kernel<<<(N + 127) / 128, 320, 0, stream>>>(hbuf, W2l, W2r, b2, p2buf, r2buf, N);
    agg2_kernel<<<(N * 64 + 255) / 256, 256, 0, stream>>>(p2buf, r2buf, rowptr, csr,
                                                          out, out + (size_t)N * D2, N);
}

// Round 9
// 202.542 us; speedup vs baseline: 1.1670x; 1.1670x over previous
//
#include <hip/hip_runtime.h>
#include <hip/hip_bf16.h>
#include <math.h>

#define N_NODES 50000
#define N_EDGES 800000
#define D0 64
#define D1 128
#define D2 40

#define NB  256   // buckets
#define NPB 196   // nodes per bucket (256*196 = 50176 >= 50000)

typedef short s16x8 __attribute__((ext_vector_type(8)));
typedef float f32x4 __attribute__((ext_vector_type(4)));

static __device__ __forceinline__ unsigned short f2bf(float v) {
    __hip_bfloat16 hb = __float2bfloat16(v);
    return *(unsigned short*)&hb;
}

// ---------------- bucketed CSR build ----------------
__global__ __launch_bounds__(256) void bucket_count_kernel(
        const int* __restrict__ dst, int* __restrict__ bcount, int E) {
    __shared__ int h[NB];
    int t = threadIdx.x;
    h[t] = 0;
    __syncthreads();
    int e0 = blockIdx.x * 2048;
    for (int i = t; i < 2048; i += 256) {
        int e = e0 + i;
        if (e < E) atomicAdd(&h[(unsigned)dst[e] / NPB], 1);
    }
    __syncthreads();
    if (h[t]) atomicAdd(&bcount[t], h[t]);
}

__global__ void bucket_scan_kernel(const int* __restrict__ bcount,
                                   int* __restrict__ bbase, int* __restrict__ bcursor) {
    __shared__ int sd[NB];
    int t = threadIdx.x;
    int v = bcount[t];
    sd[t] = v;
    __syncthreads();
    for (int off = 1; off < NB; off <<= 1) {
        int u = (t >= off) ? sd[t - off] : 0;
        __syncthreads();
        sd[t] += u;
        __syncthreads();
    }
    int ex = sd[t] - v;
    bbase[t] = ex;
    bcursor[t] = ex;
}

__global__ __launch_bounds__(256) void bucket_scatter_kernel(
        const int* __restrict__ src, const int* __restrict__ dst,
        int* __restrict__ bcursor, unsigned* __restrict__ ebuf, int E) {
    __shared__ int h[NB];
    __shared__ int base[NB];
    int t = threadIdx.x;
    int e0 = blockIdx.x * 4096;
    h[t] = 0;
    __syncthreads();
    for (int i = t; i < 4096; i += 256) {
        int e = e0 + i;
        if (e < E) atomicAdd(&h[(unsigned)dst[e] / NPB], 1);
    }
    __syncthreads();
    if (h[t] > 0) base[t] = atomicAdd(&bcursor[t], h[t]);
    h[t] = 0;
    __syncthreads();
    for (int i = t; i < 4096; i += 256) {
        int e = e0 + i;
        if (e < E) {
            unsigned d = (unsigned)dst[e];
            unsigned b = d / NPB;
            unsigned ld = d - b * NPB;
            int k = atomicAdd(&h[b], 1);
            ebuf[base[b] + k] = (ld << 17) | (unsigned)src[e];
        }
    }
}

__global__ __launch_bounds__(256) void bucket_fill_kernel(
        const unsigned* __restrict__ ebuf, const int* __restrict__ bbase,
        int* __restrict__ rowptr, int* __restrict__ csr, int E, int N) {
    __shared__ int cnt[256];
    __shared__ int sd[256];
    int b = blockIdx.x, t = threadIdx.x;
    int s0 = bbase[b];
    int s1 = (b < NB - 1) ? bbase[b + 1] : E;
    int lo = b * NPB;
    cnt[t] = 0;
    __syncthreads();
    for (int i = s0 + t; i < s1; i += 256)
        atomicAdd(&cnt[ebuf[i] >> 17], 1);
    __syncthreads();
    int v = cnt[t];
    sd[t] = v;
    __syncthreads();
    for (int off = 1; off < 256; off <<= 1) {
        int u = (t >= off) ? sd[t - off] : 0;
        __syncthreads();
        sd[t] += u;
        __syncthreads();
    }
    int ex = sd[t] - v;
    int node = lo + t;
    if (t < NPB && node < N) rowptr[node] = s0 + ex;
    cnt[t] = s0 + ex;
    __syncthreads();
    for (int i = s0 + t; i < s1; i += 256) {
        unsigned pk = ebuf[i];
        int p = atomicAdd(&cnt[pk >> 17], 1);
        csr[p] = (int)(pk & 0x1FFFFu);
    }
    if (b == NB - 1 && t == 0) rowptr[N] = E;
}

// ---------------- cast x to bf16 ----------------

__global__ void cast_x_kernel(const float* __restrict__ x, unsigned short* __restrict__ xh, int n) {
    int i = (blockIdx.x * blockDim.x + threadIdx.x) * 4;
    if (i < n) {
        float4 v = *(const float4*)(x + i);
        xh[i + 0] = f2bf(v.x);
        xh[i + 1] = f2bf(v.y);
        xh[i + 2] = f2bf(v.z);
        xh[i + 3] = f2bf(v.w);
    }
}

// ---------------- weight packing into MFMA B-fragment order (bf16) ----------------
// B-frag for mfma_f32_16x16x32_bf16: lane holds B[k = ks*32 + (lane>>4)*8 + j][n = nt*16 + (lane&15)]
// Packed: Wpk[((ks*NT + nt)*64 + lane)*8 + j]

__global__ void pack_w1_kernel(const float* __restrict__ W1l, const float* __restrict__ W1r,
                               unsigned short* __restrict__ Wpk) {
    int f = blockIdx.x;             // 32 frags: ks = f>>3, nt = f&7
    int lane = threadIdx.x;         // 64
    int nt = f & 7;
    int col = nt * 16 + (lane & 15);
    int kbase = (f >> 3) * 32 + (lane >> 4) * 8;
    unsigned short* o = Wpk + ((size_t)f * 64 + lane) * 8;
#pragma unroll
    for (int j = 0; j < 8; ++j) {
        int k = kbase + j;
        float w = (k < 64) ? W1r[k * 128 + col] : W1l[(k - 64) * 128 + col];
        o[j] = f2bf(w);
    }
}

__global__ void pack_w2_kernel(const float* __restrict__ W2l, const float* __restrict__ W2r,
                               unsigned short* __restrict__ Wpk) {
    int f = blockIdx.x;             // 20 frags: ks = f/5, nt = f%5
    int lane = threadIdx.x;
    int nt = f % 5;
    int col = nt * 16 + (lane & 15);       // 0..79
    int kbase = (f / 5) * 32 + (lane >> 4) * 8;
    unsigned short* o = Wpk + ((size_t)f * 64 + lane) * 8;
#pragma unroll
    for (int j = 0; j < 8; ++j) {
        int k = kbase + j;
        float w = (col < 40) ? W2l[k * 40 + col] : W2r[k * 40 + (col - 40)];
        o[j] = f2bf(w);
    }
}

// ---------------- agg1: 8 edges/wave-instr; outputs bf16 ----------------

__global__ void agg1_kernel(const unsigned short* __restrict__ xh, const int* __restrict__ rowptr,
                            const int* __restrict__ csr, unsigned short* __restrict__ aggh, int N) {
    int wid = (blockIdx.x * blockDim.x + threadIdx.x) >> 6;
    int lane = threadIdx.x & 63;
    if (wid >= N) return;
    int beg = rowptr[wid], end = rowptr[wid + 1];
    int deg = end - beg;
    int l = lane & 7, g = lane >> 3;
    float acc[8];
#pragma unroll
    for (int k = 0; k < 8; ++k) acc[k] = 0.f;
    int jmax = (deg + 7) >> 3;
    for (int j = 0; j < jmax; j += 2) {
        int s[2]; float w[2];
#pragma unroll
        for (int u = 0; u < 2; ++u) {
            int slot = (j + u) * 8 + g;
            int e = beg + slot;
            e = (e < end) ? e : (end - 1);
            s[u] = csr[e];
            w[u] = (slot < deg) ? 1.f : 0.f;
        }
#pragma unroll
        for (int u = 0; u < 2; ++u) {
            uint4 v = *(const uint4*)(xh + (size_t)s[u] * D0 + l * 8);
            float f0 = __uint_as_float(v.x << 16), f1 = __uint_as_float(v.x & 0xffff0000u);
            float f2 = __uint_as_float(v.y << 16), f3 = __uint_as_float(v.y & 0xffff0000u);
            float f4 = __uint_as_float(v.z << 16), f5 = __uint_as_float(v.z & 0xffff0000u);
            float f6 = __uint_as_float(v.w << 16), f7 = __uint_as_float(v.w & 0xffff0000u);
            acc[0] = fmaf(w[u], f0, acc[0]); acc[1] = fmaf(w[u], f1, acc[1]);
            acc[2] = fmaf(w[u], f2, acc[2]); acc[3] = fmaf(w[u], f3, acc[3]);
            acc[4] = fmaf(w[u], f4, acc[4]); acc[5] = fmaf(w[u], f5, acc[5]);
            acc[6] = fmaf(w[u], f6, acc[6]); acc[7] = fmaf(w[u], f7, acc[7]);
        }
    }
#pragma unroll
    for (int off = 8; off <= 32; off <<= 1) {
#pragma unroll
        for (int k = 0; k < 8; ++k) acc[k] += __shfl_xor(acc[k], off);
    }
    float inv = 1.f / (float)max(deg, 1);
    if (g == 0) {
        unsigned o0 = (unsigned)f2bf(acc[0] * inv) | ((unsigned)f2bf(acc[1] * inv) << 16);
        unsigned o1 = (unsigned)f2bf(acc[2] * inv) | ((unsigned)f2bf(acc[3] * inv) << 16);
        unsigned o2 = (unsigned)f2bf(acc[4] * inv) | ((unsigned)f2bf(acc[5] * inv) << 16);
        unsigned o3 = (unsigned)f2bf(acc[6] * inv) | ((unsigned)f2bf(acc[7] * inv) << 16);
        uint4 pk; pk.x = o0; pk.y = o1; pk.z = o2; pk.w = o3;
        *(uint4*)(aggh + (size_t)wid * D0 + l * 8) = pk;
    }
}

// ---------------- agg2 + log_softmax (fused) ----------------

__global__ void agg2_kernel(const float* __restrict__ p2, const float* __restrict__ r2,
                            const int* __restrict__ rowptr, const int* __restrict__ csr,
                            float* __restrict__ out, float* __restrict__ out2, int N) {
    int wid = (blockIdx.x * blockDim.x + threadIdx.x) >> 6;
    int lane = threadIdx.x & 63;
    if (wid >= N) return;
    int beg = rowptr[wid], end = rowptr[wid + 1];
    int deg = end - beg;
    int g = lane / 10;
    int l = lane - g * 10;
    bool gv = g < 6;
    float ax = 0.f, ay = 0.f, az = 0.f, aw = 0.f;
    int jmax = (deg + 5) / 6;
    for (int j = 0; j < jmax; j += 4) {
        int s[4]; float w[4];
#pragma unroll
        for (int u = 0; u < 4; ++u) {
            int slot = (j + u) * 6 + g;
            int e = beg + slot;
            e = (e < end) ? e : (end - 1);
            s[u] = csr[e];
            w[u] = (gv && slot < deg) ? 1.f : 0.f;
        }
#pragma unroll
        for (int u = 0; u < 4; ++u) {
            float4 v = *(const float4*)(p2 + (size_t)s[u] * D2 + l * 4);
            ax = fmaf(w[u], v.x, ax); ay = fmaf(w[u], v.y, ay);
            az = fmaf(w[u], v.z, az); aw = fmaf(w[u], v.w, aw);
        }
    }
    {
        float bx = __shfl(ax, lane + 30), by = __shfl(ay, lane + 30),
              bz = __shfl(az, lane + 30), bw = __shfl(aw, lane + 30);
        if (g < 3) { ax += bx; ay += by; az += bz; aw += bw; }
        bx = __shfl(ax, lane + 20); by = __shfl(ay, lane + 20);
        bz = __shfl(az, lane + 20); bw = __shfl(aw, lane + 20);
        if (g == 0) { ax += bx; ay += by; az += bz; aw += bw; }
        bx = __shfl(ax, lane + 10); by = __shfl(ay, lane + 10);
        bz = __shfl(az, lane + 10); bw = __shfl(aw, lane + 10);
        if (g == 0) { ax += bx; ay += by; az += bz; aw += bw; }
    }
    float inv = 1.f / (float)max(deg, 1);
    bool wr = (lane < 10);
    float4 h2;
    if (wr) {
        float4 rr = *(const float4*)(r2 + (size_t)wid * D2 + lane * 4);
        h2.x = rr.x + ax * inv; h2.y = rr.y + ay * inv;
        h2.z = rr.z + az * inv; h2.w = rr.w + aw * inv;
        *(float4*)(out + (size_t)wid * D2 + lane * 4) = h2;
    }
    float m = wr ? fmaxf(fmaxf(h2.x, h2.y), fmaxf(h2.z, h2.w)) : -INFINITY;
#pragma unroll
    for (int off = 1; off < 64; off <<= 1) m = fmaxf(m, __shfl_xor(m, off));
    float s = 0.f;
    if (wr) s = expf(h2.x - m) + expf(h2.y - m) + expf(h2.z - m) + expf(h2.w - m);
#pragma unroll
    for (int off = 1; off < 64; off <<= 1) s += __shfl_xor(s, off);
    if (wr) {
        float lg = m + logf(s);
        float4 o; o.x = h2.x - lg; o.y = h2.y - lg; o.z = h2.z - lg; o.w = h2.w - lg;
        *(float4*)(out2 + (size_t)wid * D2 + lane * 4) = o;
    }
}

// ---------------- GEMM 1 (MFMA): h = relu([x|agg]@[W1r;W1l] + b1), bf16 in/out ----------------
// Block: 128-row tile, 4 waves; wave = 32 rows x 128 cols (2 row-tiles x 8 col-tiles).
__global__ __launch_bounds__(256) void gemm1_mfma(
        const unsigned short* __restrict__ xh, const unsigned short* __restrict__ aggh,
        const unsigned short* __restrict__ Wpk, const float* __restrict__ b1,
        unsigned short* __restrict__ h, int N) {
    __shared__ __align__(16) unsigned short As[128 * 136];  // [row][k], +8 pad
    int t = threadIdx.x;
    int r0 = blockIdx.x * 128;
    // stage A: each row = 128 bf16 = 16 uint4 chunks (8 from x, 8 from agg)
    for (int i = t; i < 2048; i += 256) {
        int r = i >> 4, c = i & 15;
        int gr = r0 + r; gr = (gr < N) ? gr : (N - 1);
        uint4 v = (c < 8) ? ((const uint4*)(xh + (size_t)gr * 64))[c]
                          : ((const uint4*)(aggh + (size_t)gr * 64))[c - 8];
        *(uint4*)(As + r * 136 + c * 8) = v;
    }
    __syncthreads();
    int w = t >> 6, lane = t & 63;
    int l15 = lane & 15, q = lane >> 4;
    f32x4 zero = {0.f, 0.f, 0.f, 0.f};
    f32x4 acc[2][8];
#pragma unroll
    for (int rt = 0; rt < 2; ++rt)
#pragma unroll
        for (int nt = 0; nt < 8; ++nt) acc[rt][nt] = zero;
    const unsigned short* abase = As + (w * 32 + l15) * 136 + q * 8;
#pragma unroll
    for (int ks = 0; ks < 4; ++ks) {
        s16x8 a0 = *(const s16x8*)(abase + ks * 32);
        s16x8 a1 = *(const s16x8*)(abase + 16 * 136 + ks * 32);
        s16x8 b[8];
#pragma unroll
        for (int nt = 0; nt < 8; ++nt)
            b[nt] = *(const s16x8*)(Wpk + ((size_t)(ks * 8 + nt) * 64 + lane) * 8);
#pragma unroll
        for (int nt = 0; nt < 8; ++nt) {
            acc[0][nt] = __builtin_amdgcn_mfma_f32_16x16x32_bf16(a0, b[nt], acc[0][nt], 0, 0, 0);
            acc[1][nt] = __builtin_amdgcn_mfma_f32_16x16x32_bf16(a1, b[nt], acc[1][nt], 0, 0, 0);
        }
    }
    int rbase = r0 + w * 32 + q * 4;
#pragma unroll
    for (int nt = 0; nt < 8; ++nt) {
        int col = nt * 16 + l15;
        float bias = b1[col];
#pragma unroll
        for (int rt = 0; rt < 2; ++rt) {
#pragma unroll
            for (int reg = 0; reg < 4; ++reg) {
                int row = rbase + rt * 16 + reg;
                if (row < N)
                    h[(size_t)row * 128 + col] = f2bf(fmaxf(acc[rt][nt][reg] + bias, 0.f));
            }
        }
    }
}

// ---------------- GEMM 2 (MFMA): p2 = h@W2l, r2 = h@W2r + b2 (N=80 packed) ----------------
__global__ __launch_bounds__(256) void gemm2_mfma(
        const unsigned short* __restrict__ hq, const unsigned short* __restrict__ Wpk,
        const float* __restrict__ b2,
        float* __restrict__ p2, float* __restrict__ r2, int N) {
    __shared__ __align__(16) unsigned short As[128 * 136];
    int t = threadIdx.x;
    int r0 = blockIdx.x * 128;
    // stage A: each row = 128 bf16 = 16 uint4 chunks
    for (int i = t; i < 2048; i += 256) {
        int r = i >> 4, c = i & 15;
        int gr = r0 + r; gr = (gr < N) ? gr : (N - 1);
        uint4 v = ((const uint4*)(hq + (size_t)gr * 128))[c];
        *(uint4*)(As + r * 136 + c * 8) = v;
    }
    __syncthreads();
    int w = t >> 6, lane = t & 63;
    int l15 = lane & 15, q = lane >> 4;
    f32x4 zero = {0.f, 0.f, 0.f, 0.f};
    f32x4 acc[2][5];
#pragma unroll
    for (int rt = 0; rt < 2; ++rt)
#pragma unroll
        for (int nt = 0; nt < 5; ++nt) acc[rt][nt] = zero;
    const unsigned short* abase = As + (w * 32 + l15) * 136 + q * 8;
#pragma unroll
    for (int ks = 0; ks < 4; ++ks) {
        s16x8 a0 = *(const s16x8*)(abase + ks * 32);
        s16x8 a1 = *(const s16x8*)(abase + 16 * 136 + ks * 32);
        s16x8 b[5];
#pragma unroll
        for (int nt = 0; nt < 5; ++nt)
            b[nt] = *(const s16x8*)(Wpk + ((size_t)(ks * 5 + nt) * 64 + lane) * 8);
#pragma unroll
        for (int nt = 0; nt < 5; ++nt) {
            acc[0][nt] = __builtin_amdgcn_mfma_f32_16x16x32_bf16(a0, b[nt], acc[0][nt], 0, 0, 0);
            acc[1][nt] = __builtin_amdgcn_mfma_f32_16x16x32_bf16(a1, b[nt], acc[1][nt], 0, 0, 0);
        }
    }
    int rbase = r0 + w * 32 + q * 4;
#pragma unroll
    for (int nt = 0; nt < 5; ++nt) {
        int col = nt * 16 + l15;   // 0..79
        bool isp = col < 40;
        int oc = isp ? col : (col - 40);
        float bias = isp ? 0.f : b2[oc];
#pragma unroll
        for (int rt = 0; rt < 2; ++rt) {
#pragma unroll
            for (int reg = 0; reg < 4; ++reg) {
                int row = rbase + rt * 16 + reg;
                if (row < N) {
                    float v = acc[rt][nt][reg] + bias;
                    if (isp) p2[(size_t)row * 40 + oc] = v;
                    else     r2[(size_t)row * 40 + oc] = v;
                }
            }
        }
    }
}

// ---------------- launch ----------------

extern "C" void kernel_launch(void* const* d_in, const int* in_sizes, int n_in,
                              void* d_out, int out_size, void* d_ws, size_t ws_size,
                              hipStream_t stream) {
    const float* x   = (const float*)d_in[0];
    const int*   ei  = (const int*)d_in[1];
    const float* W1l = (const float*)d_in[2];
    const float* W1r = (const float*)d_in[3];
    const float* b1  = (const float*)d_in[4];
    const float* W2l = (const float*)d_in[5];
    const float* W2r = (const float*)d_in[6];
    const float* b2  = (const float*)d_in[7];
    float* out = (float*)d_out;

    const int N = N_NODES;
    const int E = in_sizes[1] / 2;
    const int* src = ei;
    const int* dst = ei + E;

    char* p = (char*)d_ws;
    auto alloc = [&](size_t bytes) -> void* {
        void* r = (void*)p;
        p += (bytes + 255) & ~(size_t)255;
        return r;
    };
    int*      rowptr  = (int*)alloc((size_t)(N + 1) * 4);
    int*      csr     = (int*)alloc((size_t)E * 4);
    unsigned* ebuf    = (unsigned*)alloc((size_t)E * 4);
    int*      bcount  = (int*)alloc(NB * 4);
    int*      bbase   = (int*)alloc(NB * 4);
    int*      bcursor = (int*)alloc(NB * 4);
    unsigned short* xh    = (unsigned short*)alloc((size_t)N * D0 * 2);
    unsigned short* aggh  = (unsigned short*)alloc((size_t)N * D0 * 2);
    unsigned short* hbuf  = (unsigned short*)alloc((size_t)N * D1 * 2);
    unsigned short* wpk1  = (unsigned short*)alloc((size_t)32 * 64 * 8 * 2);
    unsigned short* wpk2  = (unsigned short*)alloc((size_t)20 * 64 * 8 * 2);
    float* p2buf = (float*)alloc((size_t)N * D2 * 4);
    float* r2buf = (float*)alloc((size_t)N * D2 * 4);

    // bucketed CSR build
    hipMemsetAsync(bcount, 0, NB * 4, stream);
    bucket_count_kernel<<<(E + 2047) / 2048, 256, 0, stream>>>(dst, bcount, E);
    bucket_scan_kernel<<<1, NB, 0, stream>>>(bcount, bbase, bcursor);
    bucket_scatter_kernel<<<(E + 4095) / 4096, 256, 0, stream>>>(src, dst, bcursor, ebuf, E);
    bucket_fill_kernel<<<NB, 256, 0, stream>>>(ebuf, bbase, rowptr, csr, E, N);

    cast_x_kernel<<<(N * D0 / 4 + 255) / 256, 256, 0, stream>>>(x, xh, N * D0);
    pack_w1_kernel<<<32, 64, 0, stream>>>(W1l, W1r, wpk1);
    pack_w2_kernel<<<20, 64, 0, stream>>>(W2l, W2r, wpk2);

    // layer 1
    agg1_kernel<<<(N * 64 + 255) / 256, 256, 0, stream>>>(xh, rowptr, csr, aggh, N);
    gemm1_mfma<<<(N + 127) / 128, 256, 0, stream>>>(xh, aggh, wpk1, b1, hbuf, N);

    // layer 2: project first (linearity), gather 40-dim, fused log_softmax
    gemm2_mfma<<<(N + 127) / 128, 256, 0, stream>>>(hbuf, wpk2, b2, p2buf, r2buf, N);
    agg2_kernel<<<(N * 64 + 255) / 256, 256, 0, stream>>>(p2buf, r2buf, rowptr, csr,
                                                          out, out + (size_t)N * D2, N);
}